// Round 15
// baseline (843.880 us; speedup 1.0000x reference)
//
#include <hip/hip_runtime.h>
#include <hip/hip_bf16.h>
#include <cstdint>
#include <cstddef>

#define HIDN 2048
#define NHEAD 16
#define HDIM 128
#define INTERN 5632
#define SEQ 4096

typedef __bf16 bf16x8 __attribute__((ext_vector_type(8)));
typedef float f32x4 __attribute__((ext_vector_type(4)));
typedef float f32x16 __attribute__((ext_vector_type(16)));
typedef unsigned short u16x8 __attribute__((ext_vector_type(8)));

__device__ __forceinline__ float bf2f(unsigned short u) {
  unsigned v = ((unsigned)u) << 16; float f; __builtin_memcpy(&f, &v, 4); return f;
}
__device__ __forceinline__ unsigned short f2bf(float f) {
  unsigned u; __builtin_memcpy(&u, &f, 4);
  unsigned r = 0x7FFFu + ((u >> 16) & 1u);
  return (unsigned short)((u + r) >> 16);
}
// async global->LDS, 16B per lane. dst must be wave-linear: base + lane*16B.
__device__ __forceinline__ void gl_lds16(const unsigned short* g, unsigned short* l) {
  __builtin_amdgcn_global_load_lds((unsigned int __attribute__((address_space(1)))*)g,
                                   (unsigned int __attribute__((address_space(3)))*)l,
                                   16, 0, 0);
}
// pack two f32 -> one u32 of 2x bf16 (lo in low half)
__device__ __forceinline__ unsigned cvtpk(float lo, float hi) {
  unsigned r; asm("v_cvt_pk_bf16_f32 %0, %1, %2" : "=v"(r) : "v"(lo), "v"(hi)); return r;
}
// swap a.hi-lanes <-> b.lo-lanes
__device__ __forceinline__ void plswap(unsigned& a, unsigned& b) {
  asm("v_permlane32_swap_b32 %0, %1" : "+v"(a), "+v"(b));
}
__device__ __forceinline__ bf16x8 mk_pa(unsigned w0, unsigned w1, unsigned w2, unsigned w3) {
  union { unsigned u[4]; bf16x8 v; } t; t.u[0] = w0; t.u[1] = w1; t.u[2] = w2; t.u[3] = w3; return t.v;
}

// ---------------- RMSNorm: fp32 row -> bf16 row ----------------
__global__ __launch_bounds__(256) void rmsnorm_kernel(const float* __restrict__ x,
                                                      const float* __restrict__ wgt,
                                                      unsigned short* __restrict__ out) {
  const int tid = threadIdx.x;
  const size_t base = (size_t)blockIdx.x * HIDN + tid * 8;
  f32x4 a = *(const f32x4*)(x + base);
  f32x4 b = *(const f32x4*)(x + base + 4);
  float ss = a[0]*a[0]+a[1]*a[1]+a[2]*a[2]+a[3]*a[3]
           + b[0]*b[0]+b[1]*b[1]+b[2]*b[2]+b[3]*b[3];
#pragma unroll
  for (int off = 32; off >= 1; off >>= 1) ss += __shfl_xor(ss, off, 64);
  __shared__ float red[4];
  if ((tid & 63) == 0) red[tid >> 6] = ss;
  __syncthreads();
  float tot = red[0] + red[1] + red[2] + red[3];
  float sc = 1.f / sqrtf(tot * (1.f / HIDN) + 1e-6f);
  f32x4 w0 = *(const f32x4*)(wgt + tid * 8);
  f32x4 w1 = *(const f32x4*)(wgt + tid * 8 + 4);
  u16x8 o;
#pragma unroll
  for (int i = 0; i < 4; ++i) { o[i] = f2bf(a[i] * sc * w0[i]); o[i+4] = f2bf(b[i] * sc * w1[i]); }
  *(u16x8*)(out + base) = o;
}

// ---------------- transpose fp32 [R][C] -> bf16: out row = col*rmul + radd ----------------
__global__ __launch_bounds__(256) void transpose_f2b(const float* __restrict__ in,
                                                     unsigned short* __restrict__ out,
                                                     int R, int C, int rmul, int radd) {
  __shared__ float tile[32][33];
  const int bx = blockIdx.x * 32, by = blockIdx.y * 32;
  const int tx = threadIdx.x & 31, ty = threadIdx.x >> 5;
#pragma unroll
  for (int i = 0; i < 32; i += 8)
    tile[ty + i][tx] = in[(size_t)(by + ty + i) * C + bx + tx];
  __syncthreads();
#pragma unroll
  for (int i = 0; i < 32; i += 8)
    out[(size_t)((bx + ty + i) * rmul + radd) * R + by + tx] = f2bf(tile[tx][ty + i]);
}

// ---------------- bf16 GEMM v2: BM=128 x BN=256, BK=64, 8 waves ----------------
// EPI 1: res+acc fp32.
template<int EPI>
__global__ __launch_bounds__(512) void gemm2(const unsigned short* __restrict__ Ag,
                                             const unsigned short* __restrict__ Btg,
                                             int M, int N, int K, int nbx,
                                             float* __restrict__ outF,
                                             unsigned short* __restrict__ outB,
                                             const float* __restrict__ res) {
  __shared__ unsigned short As[2][128 * 64];
  __shared__ unsigned short Bs[2][256 * 64];
  const int tid = threadIdx.x;
  const int wid = tid >> 6, l = tid & 63;
  const int wr = wid >> 2, wc = wid & 3;
  const int lr = l & 15;
  const int lkb = ((l >> 4) & 3) << 4;
  const int arsw = (lr & 7) << 4;
  const int nwg = gridDim.x;
  const int orig = blockIdx.x;
  const int swz = (orig & 7) * (nwg >> 3) + (orig >> 3);
  const int m0 = (swz / nbx) * 128, n0 = (swz % nbx) * 256;
  const int arow = tid >> 3;
  const int scol = (((tid & 7) << 4) ^ ((arow & 7) << 4)) >> 1;

#define GSTAGE(T, B)                                                        \
  {                                                                         \
    const int k0_ = (T) << 6;                                               \
    _Pragma("unroll")                                                       \
    for (int i = 0; i < 2; ++i)                                             \
      gl_lds16(Ag + (size_t)(m0 + i * 64 + arow) * K + k0_ + scol,          \
               &As[B][(i * 512 + tid) * 8]);                                \
    _Pragma("unroll")                                                       \
    for (int i = 0; i < 4; ++i)                                             \
      gl_lds16(Btg + (size_t)(n0 + i * 64 + arow) * K + k0_ + scol,         \
               &Bs[B][(i * 512 + tid) * 8]);                                \
  }
#define LDA(B, mf, ks) (*(const bf16x8*)&As[B][(wr * 64 + (mf) * 16 + lr) * 64 + (((((ks) << 6) | lkb) ^ arsw) >> 1)])
#define LDB(B, nf, ks) (*(const bf16x8*)&Bs[B][(wc * 64 + (nf) * 16 + lr) * 64 + (((((ks) << 6) | lkb) ^ arsw) >> 1)])

  f32x4 acc[4][4];
#pragma unroll
  for (int i = 0; i < 4; ++i)
#pragma unroll
    for (int j = 0; j < 4; ++j) acc[i][j] = (f32x4){0.f, 0.f, 0.f, 0.f};

  GSTAGE(0, 0);
  GSTAGE(1, 1);
  asm volatile("s_waitcnt vmcnt(6)" ::: "memory");
  __builtin_amdgcn_sched_barrier(0);
  __builtin_amdgcn_s_barrier();

  const int NT = K >> 6;
  for (int t = 0; t < NT; ++t) {
    const int cur = t & 1;
    bf16x8 a0[4], b0[4], a1[4], b1[4];
#pragma unroll
    for (int mf = 0; mf < 4; ++mf) a0[mf] = LDA(cur, mf, 0);
#pragma unroll
    for (int nf = 0; nf < 4; ++nf) b0[nf] = LDB(cur, nf, 0);
#pragma unroll
    for (int mf = 0; mf < 4; ++mf) a1[mf] = LDA(cur, mf, 1);
#pragma unroll
    for (int nf = 0; nf < 4; ++nf) b1[nf] = LDB(cur, nf, 1);
    __builtin_amdgcn_s_setprio(1);
#pragma unroll
    for (int mf = 0; mf < 4; ++mf)
#pragma unroll
      for (int nf = 0; nf < 4; ++nf)
        acc[mf][nf] = __builtin_amdgcn_mfma_f32_16x16x32_bf16(a0[mf], b0[nf], acc[mf][nf], 0, 0, 0);
    __builtin_amdgcn_s_setprio(0);
    asm volatile("s_waitcnt lgkmcnt(0)" ::: "memory");
    __builtin_amdgcn_sched_barrier(0);
    __builtin_amdgcn_s_barrier();
    if (t + 2 < NT) GSTAGE(t + 2, cur);
    __builtin_amdgcn_s_setprio(1);
#pragma unroll
    for (int mf = 0; mf < 4; ++mf)
#pragma unroll
      for (int nf = 0; nf < 4; ++nf)
        acc[mf][nf] = __builtin_amdgcn_mfma_f32_16x16x32_bf16(a1[mf], b1[nf], acc[mf][nf], 0, 0, 0);
    __builtin_amdgcn_s_setprio(0);
    if (t + 2 < NT) { asm volatile("s_waitcnt vmcnt(6)" ::: "memory"); }
    else            { asm volatile("s_waitcnt vmcnt(0)" ::: "memory"); }
    __builtin_amdgcn_sched_barrier(0);
    __builtin_amdgcn_s_barrier();
  }
#undef GSTAGE
#undef LDA
#undef LDB

#pragma unroll
  for (int mf = 0; mf < 4; ++mf)
#pragma unroll
    for (int nf = 0; nf < 4; ++nf)
#pragma unroll
      for (int r = 0; r < 4; ++r) {
        const int row = m0 + wr * 64 + mf * 16 + (l >> 4) * 4 + r;
        const int col = n0 + wc * 64 + nf * 16 + lr;
        float v = acc[mf][nf][r];
        if (EPI == 0) {
          outB[(size_t)row * N + col] = f2bf(v);
        } else {
          const size_t idx = (size_t)row * N + col;
          outF[idx] = res[idx] + v;
        }
      }
}

// ---------------- bf16 GEMM v3: BM=256 x BN=256, BK=64, 8 waves (wave tile 128x64) ----------------
// EPI 3: fused QKV epilogue — RoPE on q/k (adjacent-lane pairs), v stored transposed
//        into vt ([d][SEQ]). EPI 5: interleaved gate/up -> silu(g)*u (stride INTERN).
template<int EPI>
__global__ __launch_bounds__(512, 2) void gemm3(const unsigned short* __restrict__ Ag,
                                                const unsigned short* __restrict__ Btg,
                                                int M, int N, int K, int nbx,
                                                unsigned short* __restrict__ outB,
                                                const float* __restrict__ cosb,
                                                const float* __restrict__ sinb,
                                                unsigned short* __restrict__ qb_,
                                                unsigned short* __restrict__ kb_,
                                                unsigned short* __restrict__ vt_) {
  __shared__ unsigned short As[2][256 * 64];
  __shared__ unsigned short Bs[2][256 * 64];
  const int tid = threadIdx.x;
  const int wid = tid >> 6, l = tid & 63;
  const int wr = wid >> 2, wc = wid & 3;        // 2 x 4 waves; wave tile 128 x 64
  const int lr = l & 15;
  const int lkb = ((l >> 4) & 3) << 4;
  const int arsw = (lr & 7) << 4;
  const int nwg = gridDim.x;
  const int orig = blockIdx.x;
  const int swz = (orig & 7) * (nwg >> 3) + (orig >> 3);
  const int m0 = (swz / nbx) * 256, n0 = (swz % nbx) * 256;
  const int arow = tid >> 3;
  const int scol = (((tid & 7) << 4) ^ ((arow & 7) << 4)) >> 1;

#define G3STAGE(T, B)                                                       \
  {                                                                         \
    const int k0_ = (T) << 6;                                               \
    _Pragma("unroll")                                                       \
    for (int i = 0; i < 4; ++i)                                             \
      gl_lds16(Ag + (size_t)(m0 + i * 64 + arow) * K + k0_ + scol,          \
               &As[B][(i * 512 + tid) * 8]);                                \
    _Pragma("unroll")                                                       \
    for (int i = 0; i < 4; ++i)                                             \
      gl_lds16(Btg + (size_t)(n0 + i * 64 + arow) * K + k0_ + scol,         \
               &Bs[B][(i * 512 + tid) * 8]);                                \
  }
#define LDA3(B, mf, ks) (*(const bf16x8*)&As[B][(wr * 128 + (mf) * 16 + lr) * 64 + (((((ks) << 6) | lkb) ^ arsw) >> 1)])
#define LDB3(B, nf, ks) (*(const bf16x8*)&Bs[B][(wc * 64 + (nf) * 16 + lr) * 64 + (((((ks) << 6) | lkb) ^ arsw) >> 1)])

  f32x4 acc[8][4];
#pragma unroll
  for (int i = 0; i < 8; ++i)
#pragma unroll
    for (int j = 0; j < 4; ++j) acc[i][j] = (f32x4){0.f, 0.f, 0.f, 0.f};

  G3STAGE(0, 0);
  G3STAGE(1, 1);
  asm volatile("s_waitcnt vmcnt(8)" ::: "memory");
  __builtin_amdgcn_sched_barrier(0);
  __builtin_amdgcn_s_barrier();

  const int NT = K >> 6;
  for (int t = 0; t < NT; ++t) {
    const int cur = t & 1;
    {
      bf16x8 a0[8], b0[4];
#pragma unroll
      for (int mf = 0; mf < 8; ++mf) a0[mf] = LDA3(cur, mf, 0);
#pragma unroll
      for (int nf = 0; nf < 4; ++nf) b0[nf] = LDB3(cur, nf, 0);
      __builtin_amdgcn_s_setprio(1);
#pragma unroll
      for (int mf = 0; mf < 8; ++mf)
#pragma unroll
        for (int nf = 0; nf < 4; ++nf)
          acc[mf][nf] = __builtin_amdgcn_mfma_f32_16x16x32_bf16(a0[mf], b0[nf], acc[mf][nf], 0, 0, 0);
      __builtin_amdgcn_s_setprio(0);
    }
    bf16x8 a1[8], b1[4];
#pragma unroll
    for (int mf = 0; mf < 8; ++mf) a1[mf] = LDA3(cur, mf, 1);
#pragma unroll
    for (int nf = 0; nf < 4; ++nf) b1[nf] = LDB3(cur, nf, 1);
    asm volatile("s_waitcnt lgkmcnt(0)" ::: "memory");
    __builtin_amdgcn_sched_barrier(0);
    __builtin_amdgcn_s_barrier();
    if (t + 2 < NT) G3STAGE(t + 2, cur);
    __builtin_amdgcn_s_setprio(1);
#pragma unroll
    for (int mf = 0; mf < 8; ++mf)
#pragma unroll
      for (int nf = 0; nf < 4; ++nf)
        acc[mf][nf] = __builtin_amdgcn_mfma_f32_16x16x32_bf16(a1[mf], b1[nf], acc[mf][nf], 0, 0, 0);
    __builtin_amdgcn_s_setprio(0);
    if (t + 2 < NT) { asm volatile("s_waitcnt vmcnt(8)" ::: "memory"); }
    else            { asm volatile("s_waitcnt vmcnt(0)" ::: "memory"); }
    __builtin_amdgcn_sched_barrier(0);
    __builtin_amdgcn_s_barrier();
  }
#undef G3STAGE
#undef LDA3
#undef LDB3

#pragma unroll
  for (int mf = 0; mf < 8; ++mf)
#pragma unroll
    for (int nf = 0; nf < 4; ++nf)
#pragma unroll
      for (int r = 0; r < 4; ++r) {
        const int row = m0 + wr * 128 + mf * 16 + (l >> 4) * 4 + r;
        const int col = n0 + wc * 64 + nf * 16 + lr;
        float v = acc[mf][nf][r];
        if (EPI == 3) {
          if (col < 4096) {
            // RoPE: col parity == lr parity; pair shares (mf,nf,r) => same row.
            const float other = __shfl_xor(v, 1, 64);
            const int d = col & 127;
            const float c = cosb[(size_t)row * 64 + (d >> 1)];
            const float s = sinb[(size_t)row * 64 + (d >> 1)];
            // even lane: v=real, other=imag -> re' = v*c - other*s
            // odd  lane: v=imag, other=real -> im' = other*s + v*c
            const float rv = ((lr & 1) == 0) ? (v * c - other * s) : (other * s + v * c);
            unsigned short* dst = (col < 2048) ? qb_ : kb_;
            dst[(size_t)row * 2048 + (col & 2047)] = f2bf(rv);
          } else {
            // v stored transposed: vt[d][row]
            vt_[(size_t)(col - 4096) * SEQ + row] = f2bf(v);
          }
        } else {
          // EPI 5: interleaved gate/up: even col = gate_c, odd col = up_c (c = col>>1)
          const float other = __shfl_xor(v, 1, 64);
          if ((lr & 1) == 0) {
            const float g = v, u = other;
            outB[(size_t)row * INTERN + (col >> 1)] = f2bf(u * g / (1.f + __expf(-g)));
          }
        }
      }
}

// ---------------- causal flash attention v5: both pair-jobs concurrent ----------------
// Q pre-scaled by softmax-scale*log2e at load -> S emerges in exp2 domain.
__global__ __launch_bounds__(512) void attn_kernel(const unsigned short* __restrict__ Q,
                                                   const unsigned short* __restrict__ Kb,
                                                   const unsigned short* __restrict__ Vt,
                                                   unsigned short* __restrict__ Ob) {
  __shared__ unsigned short Ks[2][64 * 128];   // [kv][d], 256B rows, (row&15)<<4 swizzle
  __shared__ unsigned short Vs[2][128 * 64];   // [d][kv], 128B rows, (row&7)<<4 swizzle
  __shared__ float alS[8][32];
  __shared__ unsigned short pad[8192];         // occupancy limiter: LDS > 80KB -> 1 block/CU
  const int tid = threadIdx.x, w = tid >> 6, l = tid & 63;
  const int lq = l & 31, hi = l >> 5;
  const int bid = blockIdx.x;
  const int h = 2 * (bid & 7) + ((bid >> 3) & 1);   // head pinned to XCD (L2 affinity)
  const int pp = bid >> 4;                          // 0..15
  if (gridDim.y == 2) { pad[tid] = 1; Ob[0] = pad[tid ^ 1]; }  // never true; keeps pad live

  const int j = (w < 4) ? (31 - pp) : pp;   // job A (heavy) / job B (light)
  const int qb0 = j * 128;
  const int qw0 = qb0 + (w & 3) * 32;
  const int ntA = (31 - pp) * 2 + 2;        // block-uniform loop bound (job A range)

  const float SC2 = 0.08838834764831845f * 1.44269504088896f;
  bf16x8 qf[8];
#pragma unroll
  for (int cq = 0; cq < 8; ++cq) {
    u16x8 uq = *(const u16x8*)(Q + (size_t)(qw0 + lq) * HIDN + h * HDIM + cq * 16 + hi * 8);
    u16x8 oq;
#pragma unroll
    for (int e = 0; e < 8; ++e) oq[e] = f2bf(bf2f(uq[e]) * SC2);
    __builtin_memcpy(&qf[cq], &oq, 16);
  }

  float m2 = -1e30f, lsum = 0.f;
  f32x16 o[4];
#pragma unroll
  for (int dc = 0; dc < 4; ++dc) o[dc] = (f32x16){};

  const int krow = tid >> 4, kc2 = (tid & 15) * 16;
  const int vrow = tid >> 3, vc2 = (tid & 7) * 16;

#define STAGE(T, B)                                                                          \
  {                                                                                          \
    const int kv0_ = (T) * 64;                                                               \
    _Pragma("unroll")                                                                        \
    for (int i_ = 0; i_ < 2; ++i_) {                                                         \
      const int row = i_ * 32 + krow;                                                        \
      gl_lds16(Kb + (size_t)(kv0_ + row) * HIDN + h * HDIM + ((kc2 ^ ((row & 15) << 4)) >> 1), \
               &Ks[B][i_ * 4096 + tid * 8]);                                                 \
    }                                                                                        \
    _Pragma("unroll")                                                                        \
    for (int i_ = 0; i_ < 2; ++i_) {                                                         \
      const int row = i_ * 64 + vrow;                                                        \
      gl_lds16(Vt + (size_t)(h * HDIM + row) * SEQ + kv0_ + ((vc2 ^ ((row & 7) << 4)) >> 1),   \
               &Vs[B][i_ * 4096 + tid * 8]);                                                 \
    }                                                                                        \
  }
#define LDK(row_, c_) (*(const bf16x8*)&Ks[cur][(row_) * 128 + ((((c_) * 32 + hi * 16) ^ (((row_) & 15) << 4)) >> 1)])
#define LDV(row_, ks_) (*(const bf16x8*)&Vs[cur][(row_) * 64 + ((((ks_) * 32 + hi * 16) ^ (((row_) & 7) << 4)) >> 1)])

  STAGE(0, 0);
  __syncthreads();

  for (int t = 0; t < ntA; ++t) {
    const int cur = t & 1, kv0 = t * 64;
    if (t + 1 < ntA) STAGE(t + 1, cur ^ 1);

    if (kv0 <= qw0 + 31) {
      f32x16 s0 = {}, s1 = {};
      __builtin_amdgcn_s_setprio(1);
#pragma unroll
      for (int cq = 0; cq < 8; ++cq) {
        s0 = __builtin_amdgcn_mfma_f32_32x32x16_bf16(LDK(lq, cq), qf[cq], s0, 0, 0, 0);
        s1 = __builtin_amdgcn_mfma_f32_32x32x16_bf16(LDK(32 + lq, cq), qf[cq], s1, 0, 0, 0);
      }
      __builtin_amdgcn_s_setprio(0);
      if (kv0 + 63 > qw0) {
        const int qi = qw0 + lq;
#pragma unroll
        for (int r = 0; r < 16; ++r) {
          const int kvr = kv0 + (r & 3) + 8 * (r >> 2) + 4 * hi;
          if (kvr > qi) s0[r] = -1e30f;
          if (kvr + 32 > qi) s1[r] = -1e30f;
        }
      }
      float vm = s0[0];
#pragma unroll
      for (int r = 1; r < 16; ++r) vm = fmaxf(vm, s0[r]);
#pragma unroll
      for (int r = 0; r < 16; ++r) vm = fmaxf(vm, s1[r]);
      vm = fmaxf(vm, __shfl_xor(vm, 32, 64));
      float al = 1.f;
      if (!__all(vm <= m2 + 11.54f)) {
        const float mn = fmaxf(m2, vm);
        al = exp2f(m2 - mn);
        m2 = mn;
        if (l < 32) alS[w][l] = al;
#pragma unroll
        for (int r = 0; r < 16; ++r) {
          const float a = alS[w][(r & 3) + 8 * (r >> 2) + 4 * hi];
          o[0][r] *= a; o[1][r] *= a; o[2][r] *= a; o[3][r] *= a;
        }
      }
      float p[32];
#pragma unroll
      for (int r = 0; r < 16; ++r) { p[r] = exp2f(s0[r] - m2); p[16 + r] = exp2f(s1[r] - m2); }
      float rsum = 0.f;
#pragma unroll
      for (int r = 0; r < 32; ++r) rsum += p[r];
      lsum = lsum * al + (rsum + __shfl_xor(rsum, 32, 64));
      bf16x8 pa[4];
#pragma unroll
      for (int hh = 0; hh < 2; ++hh) {
        unsigned ua[8];
#pragma unroll
        for (int i_ = 0; i_ < 8; ++i_) ua[i_] = cvtpk(p[hh * 16 + 2 * i_], p[hh * 16 + 2 * i_ + 1]);
        plswap(ua[0], ua[2]); plswap(ua[1], ua[3]);
        plswap(ua[4], ua[6]); plswap(ua[5], ua[7]);
        pa[hh * 2]     = mk_pa(ua[0], ua[1], ua[2], ua[3]);
        pa[hh * 2 + 1] = mk_pa(ua[4], ua[5], ua[6], ua[7]);
      }
      __builtin_amdgcn_s_setprio(1);
#pragma unroll
      for (int dc = 0; dc < 4; ++dc) {
        const int vr = dc * 32 + lq;
#pragma unroll
        for (int ks = 0; ks < 4; ++ks)
          o[dc] = __builtin_amdgcn_mfma_f32_32x32x16_bf16(pa[ks], LDV(vr, ks), o[dc], 0, 0, 0);
      }
      __builtin_amdgcn_s_setprio(0);
    }
    __syncthreads();
  }
#undef STAGE
#undef LDK
#undef LDV

  if (l < 32) alS[w][l] = 1.f / lsum;
#pragma unroll
  for (int r = 0; r < 16; ++r) {
    const int q = (r & 3) + 8 * (r >> 2) + 4 * hi;
    const float rr = alS[w][q];
    const size_t rowb = (size_t)(qw0 + q) * HIDN + h * HDIM + lq;
    Ob[rowb]      = f2bf(o[0][r] * rr);
    Ob[rowb + 32] = f2bf(o[1][r] * rr);
    Ob[rowb + 64] = f2bf(o[2][r] * rr);
    Ob[rowb + 96] = f2bf(o[3][r] * rr);
  }
}

extern "C" void kernel_launch(void* const* d_in, const int* in_sizes, int n_in,
                              void* d_out, int out_size, void* d_ws, size_t ws_size,
                              hipStream_t stream) {
  const float* x    = (const float*)d_in[0];
  const float* fcos = (const float*)d_in[1];
  const float* fsin = (const float*)d_in[2];
  // d_in[3] = mask: causal computed directly
  const float* wq = (const float*)d_in[4];
  const float* wk = (const float*)d_in[5];
  const float* wv = (const float*)d_in[6];
  const float* wo = (const float*)d_in[7];
  const float* wg = (const float*)d_in[8];
  const float* wu = (const float*)d_in[9];
  const float* wd = (const float*)d_in[10];
  const float* n1 = (const float*)d_in[11];
  const float* n2 = (const float*)d_in[12];
  float* out = (float*)d_out;

  const size_t HH = (size_t)HIDN * HIDN, HI = (size_t)HIDN * INTERN;
  const size_t SH = (size_t)SEQ * HIDN, SI = (size_t)SEQ * INTERN;
  unsigned short* p = (unsigned short*)d_ws;
  unsigned short* wqT = p; p += HH;   // wqT|wkT|wvT contiguous => fused QKV B [6144][2048]
  unsigned short* wkT = p; p += HH;
  unsigned short* wvT = p; p += HH;
  unsigned short* woT = p; p += HH;
  unsigned short* wguT = p; p += 2 * HI;  // interleaved gate/up B [11264][2048]
  unsigned short* wdT = p; p += HI;
  unsigned short* xn  = p; p += SH;   // xn, later hn
  unsigned short* qb  = p; p += SH;
  unsigned short* kb  = p; p += SH;
  unsigned short* vb  = p; p += SH;   // attention out
  unsigned short* vt  = p; p += SH;   // v transposed [HIDN][SEQ] (per-head [128][SEQ])
  unsigned short* ffnb = p; p += SI;
  float* hbuf = (float*)p;            // SH floats

  rmsnorm_kernel<<<SEQ, 256, 0, stream>>>(x, n1, xn);
  dim3 tHH(HIDN / 32, HIDN / 32);
  transpose_f2b<<<tHH, 256, 0, stream>>>(wq, wqT, HIDN, HIDN, 1, 0);
  transpose_f2b<<<tHH, 256, 0, stream>>>(wk, wkT, HIDN, HIDN, 1, 0);
  transpose_f2b<<<tHH, 256, 0, stream>>>(wv, wvT, HIDN, HIDN, 1, 0);
  transpose_f2b<<<tHH, 256, 0, stream>>>(wo, woT, HIDN, HIDN, 1, 0);
  transpose_f2b<<<dim3(INTERN / 32, HIDN / 32), 256, 0, stream>>>(wg, wguT, HIDN, INTERN, 2, 0);
  transpose_f2b<<<dim3(INTERN / 32, HIDN / 32), 256, 0, stream>>>(wu, wguT, HIDN, INTERN, 2, 1);
  transpose_f2b<<<dim3(HIDN / 32, INTERN / 32), 256, 0, stream>>>(wd, wdT, INTERN, HIDN, 1, 0);

  // fused QKV + RoPE + V-transpose: C[4096][6144] -> qb (roped), kb (roped), vt (transposed)
  gemm3<3><<<384, 512, 0, stream>>>(xn, wqT, SEQ, 3 * HIDN, HIDN, 24,
                                    nullptr, fcos, fsin, qb, kb, vt);
  attn_kernel<<<dim3(256), 512, 0, stream>>>(qb, kb, vt, vb);
  gemm2<1><<<256, 512, 0, stream>>>(vb, woT, SEQ, HIDN, HIDN, 8, hbuf, nullptr, x);
  rmsnorm_kernel<<<SEQ, 256, 0, stream>>>(hbuf, n2, xn);
  // fused+interleaved gate/up: C[4096][11264] -> silu(gate)*up stored directly to ffnb
  gemm3<5><<<704, 512, 0, stream>>>(xn, wguT, SEQ, 2 * INTERN, HIDN, 44,
                                    ffnb, nullptr, nullptr, nullptr, nullptr, nullptr);
  gemm2<1><<<256, 512, 0, stream>>>(ffnb, wdT, SEQ, HIDN, INTERN, 8, out, nullptr, hbuf);
}

// Round 16
// 767.748 us; speedup vs baseline: 1.0992x; 1.0992x over previous
//
#include <hip/hip_runtime.h>
#include <hip/hip_bf16.h>
#include <cstdint>
#include <cstddef>

#define HIDN 2048
#define NHEAD 16
#define HDIM 128
#define INTERN 5632
#define SEQ 4096

typedef __bf16 bf16x8 __attribute__((ext_vector_type(8)));
typedef float f32x4 __attribute__((ext_vector_type(4)));
typedef float f32x16 __attribute__((ext_vector_type(16)));
typedef unsigned short u16x8 __attribute__((ext_vector_type(8)));

__device__ __forceinline__ float bf2f(unsigned short u) {
  unsigned v = ((unsigned)u) << 16; float f; __builtin_memcpy(&f, &v, 4); return f;
}
__device__ __forceinline__ unsigned short f2bf(float f) {
  unsigned u; __builtin_memcpy(&u, &f, 4);
  unsigned r = 0x7FFFu + ((u >> 16) & 1u);
  return (unsigned short)((u + r) >> 16);
}
// async global->LDS, 16B per lane. dst must be wave-linear: base + lane*16B.
__device__ __forceinline__ void gl_lds16(const unsigned short* g, unsigned short* l) {
  __builtin_amdgcn_global_load_lds((unsigned int __attribute__((address_space(1)))*)g,
                                   (unsigned int __attribute__((address_space(3)))*)l,
                                   16, 0, 0);
}
// pack two f32 -> one u32 of 2x bf16 (lo in low half)
__device__ __forceinline__ unsigned cvtpk(float lo, float hi) {
  unsigned r; asm("v_cvt_pk_bf16_f32 %0, %1, %2" : "=v"(r) : "v"(lo), "v"(hi)); return r;
}
// swap a.hi-lanes <-> b.lo-lanes
__device__ __forceinline__ void plswap(unsigned& a, unsigned& b) {
  asm("v_permlane32_swap_b32 %0, %1" : "+v"(a), "+v"(b));
}
__device__ __forceinline__ bf16x8 mk_pa(unsigned w0, unsigned w1, unsigned w2, unsigned w3) {
  union { unsigned u[4]; bf16x8 v; } t; t.u[0] = w0; t.u[1] = w1; t.u[2] = w2; t.u[3] = w3; return t.v;
}

// ---------------- RMSNorm: fp32 row -> bf16 row ----------------
__global__ __launch_bounds__(256) void rmsnorm_kernel(const float* __restrict__ x,
                                                      const float* __restrict__ wgt,
                                                      unsigned short* __restrict__ out) {
  const int tid = threadIdx.x;
  const size_t base = (size_t)blockIdx.x * HIDN + tid * 8;
  f32x4 a = *(const f32x4*)(x + base);
  f32x4 b = *(const f32x4*)(x + base + 4);
  float ss = a[0]*a[0]+a[1]*a[1]+a[2]*a[2]+a[3]*a[3]
           + b[0]*b[0]+b[1]*b[1]+b[2]*b[2]+b[3]*b[3];
#pragma unroll
  for (int off = 32; off >= 1; off >>= 1) ss += __shfl_xor(ss, off, 64);
  __shared__ float red[4];
  if ((tid & 63) == 0) red[tid >> 6] = ss;
  __syncthreads();
  float tot = red[0] + red[1] + red[2] + red[3];
  float sc = 1.f / sqrtf(tot * (1.f / HIDN) + 1e-6f);
  f32x4 w0 = *(const f32x4*)(wgt + tid * 8);
  f32x4 w1 = *(const f32x4*)(wgt + tid * 8 + 4);
  u16x8 o;
#pragma unroll
  for (int i = 0; i < 4; ++i) { o[i] = f2bf(a[i] * sc * w0[i]); o[i+4] = f2bf(b[i] * sc * w1[i]); }
  *(u16x8*)(out + base) = o;
}

// ---------------- transpose fp32 [R][C] -> bf16: out row = col*rmul + radd ----------------
__global__ __launch_bounds__(256) void transpose_f2b(const float* __restrict__ in,
                                                     unsigned short* __restrict__ out,
                                                     int R, int C, int rmul, int radd) {
  __shared__ float tile[32][33];
  const int bx = blockIdx.x * 32, by = blockIdx.y * 32;
  const int tx = threadIdx.x & 31, ty = threadIdx.x >> 5;
#pragma unroll
  for (int i = 0; i < 32; i += 8)
    tile[ty + i][tx] = in[(size_t)(by + ty + i) * C + bx + tx];
  __syncthreads();
#pragma unroll
  for (int i = 0; i < 32; i += 8)
    out[(size_t)((bx + ty + i) * rmul + radd) * R + by + tx] = f2bf(tile[tx][ty + i]);
}

// ---------------- transpose bf16 [R][C] -> bf16 [C][R] ----------------
__global__ __launch_bounds__(256) void transpose_b2b(const unsigned short* __restrict__ in,
                                                     unsigned short* __restrict__ out,
                                                     int R, int C) {
  __shared__ unsigned short tile[32][33];
  const int bx = blockIdx.x * 32, by = blockIdx.y * 32;
  const int tx = threadIdx.x & 31, ty = threadIdx.x >> 5;
#pragma unroll
  for (int i = 0; i < 32; i += 8)
    tile[ty + i][tx] = in[(size_t)(by + ty + i) * C + bx + tx];
  __syncthreads();
#pragma unroll
  for (int i = 0; i < 32; i += 8)
    out[(size_t)(bx + ty + i) * R + by + tx] = tile[tx][ty + i];
}

// ---------------- RoPE in-place on bf16 [SEQ][HIDN] ----------------
__global__ __launch_bounds__(256) void rope_kernel(unsigned short* __restrict__ v,
                                                   const float* __restrict__ cosb,
                                                   const float* __restrict__ sinb) {
  const int s = blockIdx.x, tid = threadIdx.x;
  const size_t base = (size_t)s * HIDN + tid * 8;
  u16x8 u = *(const u16x8*)(v + base);
  const int j0 = ((tid * 8) & 127) >> 1;
  const float* cr = cosb + s * 64 + j0;
  const float* sr = sinb + s * 64 + j0;
  u16x8 o;
#pragma unroll
  for (int p = 0; p < 4; ++p) {
    float re = bf2f(u[2*p]), im = bf2f(u[2*p+1]);
    float c = cr[p], sn = sr[p];
    o[2*p]   = f2bf(re * c - im * sn);
    o[2*p+1] = f2bf(re * sn + im * c);
  }
  *(u16x8*)(v + base) = o;
}

// ---------------- bf16 GEMM v2: BM=128 x BN=256, BK=64, 8 waves ----------------
// EPI 0: bf16(acc); 1: res+acc fp32; 2: silu(gate)*acc; 3: qkv split (N=6144).
template<int EPI>
__global__ __launch_bounds__(512) void gemm2(const unsigned short* __restrict__ Ag,
                                             const unsigned short* __restrict__ Btg,
                                             int M, int N, int K, int nbx,
                                             float* __restrict__ outF,
                                             unsigned short* __restrict__ outB,
                                             const float* __restrict__ res,
                                             const unsigned short* __restrict__ gate,
                                             unsigned short* __restrict__ qb_,
                                             unsigned short* __restrict__ kb_,
                                             unsigned short* __restrict__ vb_) {
  __shared__ unsigned short As[2][128 * 64];
  __shared__ unsigned short Bs[2][256 * 64];
  const int tid = threadIdx.x;
  const int wid = tid >> 6, l = tid & 63;
  const int wr = wid >> 2, wc = wid & 3;
  const int lr = l & 15;
  const int lkb = ((l >> 4) & 3) << 4;
  const int arsw = (lr & 7) << 4;
  const int nwg = gridDim.x;
  const int orig = blockIdx.x;
  const int swz = (orig & 7) * (nwg >> 3) + (orig >> 3);
  const int m0 = (swz / nbx) * 128, n0 = (swz % nbx) * 256;
  const int arow = tid >> 3;
  const int scol = (((tid & 7) << 4) ^ ((arow & 7) << 4)) >> 1;

#define GSTAGE(T, B)                                                        \
  {                                                                         \
    const int k0_ = (T) << 6;                                               \
    _Pragma("unroll")                                                       \
    for (int i = 0; i < 2; ++i)                                             \
      gl_lds16(Ag + (size_t)(m0 + i * 64 + arow) * K + k0_ + scol,          \
               &As[B][(i * 512 + tid) * 8]);                                \
    _Pragma("unroll")                                                       \
    for (int i = 0; i < 4; ++i)                                             \
      gl_lds16(Btg + (size_t)(n0 + i * 64 + arow) * K + k0_ + scol,         \
               &Bs[B][(i * 512 + tid) * 8]);                                \
  }
#define LDA(B, mf, ks) (*(const bf16x8*)&As[B][(wr * 64 + (mf) * 16 + lr) * 64 + (((((ks) << 6) | lkb) ^ arsw) >> 1)])
#define LDB(B, nf, ks) (*(const bf16x8*)&Bs[B][(wc * 64 + (nf) * 16 + lr) * 64 + (((((ks) << 6) | lkb) ^ arsw) >> 1)])

  f32x4 acc[4][4];
#pragma unroll
  for (int i = 0; i < 4; ++i)
#pragma unroll
    for (int j = 0; j < 4; ++j) acc[i][j] = (f32x4){0.f, 0.f, 0.f, 0.f};

  GSTAGE(0, 0);
  GSTAGE(1, 1);
  asm volatile("s_waitcnt vmcnt(6)" ::: "memory");
  __builtin_amdgcn_sched_barrier(0);
  __builtin_amdgcn_s_barrier();

  const int NT = K >> 6;
  for (int t = 0; t < NT; ++t) {
    const int cur = t & 1;
    bf16x8 a0[4], b0[4], a1[4], b1[4];
#pragma unroll
    for (int mf = 0; mf < 4; ++mf) a0[mf] = LDA(cur, mf, 0);
#pragma unroll
    for (int nf = 0; nf < 4; ++nf) b0[nf] = LDB(cur, nf, 0);
#pragma unroll
    for (int mf = 0; mf < 4; ++mf) a1[mf] = LDA(cur, mf, 1);
#pragma unroll
    for (int nf = 0; nf < 4; ++nf) b1[nf] = LDB(cur, nf, 1);
    __builtin_amdgcn_s_setprio(1);
#pragma unroll
    for (int mf = 0; mf < 4; ++mf)
#pragma unroll
      for (int nf = 0; nf < 4; ++nf)
        acc[mf][nf] = __builtin_amdgcn_mfma_f32_16x16x32_bf16(a0[mf], b0[nf], acc[mf][nf], 0, 0, 0);
    __builtin_amdgcn_s_setprio(0);
    asm volatile("s_waitcnt lgkmcnt(0)" ::: "memory");
    __builtin_amdgcn_sched_barrier(0);
    __builtin_amdgcn_s_barrier();
    if (t + 2 < NT) GSTAGE(t + 2, cur);
    __builtin_amdgcn_s_setprio(1);
#pragma unroll
    for (int mf = 0; mf < 4; ++mf)
#pragma unroll
      for (int nf = 0; nf < 4; ++nf)
        acc[mf][nf] = __builtin_amdgcn_mfma_f32_16x16x32_bf16(a1[mf], b1[nf], acc[mf][nf], 0, 0, 0);
    __builtin_amdgcn_s_setprio(0);
    if (t + 2 < NT) { asm volatile("s_waitcnt vmcnt(6)" ::: "memory"); }
    else            { asm volatile("s_waitcnt vmcnt(0)" ::: "memory"); }
    __builtin_amdgcn_sched_barrier(0);
    __builtin_amdgcn_s_barrier();
  }
#undef GSTAGE
#undef LDA
#undef LDB

#pragma unroll
  for (int mf = 0; mf < 4; ++mf)
#pragma unroll
    for (int nf = 0; nf < 4; ++nf)
#pragma unroll
      for (int r = 0; r < 4; ++r) {
        const int row = m0 + wr * 64 + mf * 16 + (l >> 4) * 4 + r;
        const int col = n0 + wc * 64 + nf * 16 + lr;
        float v = acc[mf][nf][r];
        if (EPI == 0) {
          outB[(size_t)row * N + col] = f2bf(v);
        } else if (EPI == 1) {
          const size_t idx = (size_t)row * N + col;
          outF[idx] = res[idx] + v;
        } else if (EPI == 2) {
          const size_t idx = (size_t)row * N + col;
          float g = bf2f(gate[idx]);
          outB[idx] = f2bf(v * g / (1.f + __expf(-g)));
        } else {
          unsigned short* dst = (col < 2048) ? qb_ : (col < 4096) ? kb_ : vb_;
          dst[(size_t)row * 2048 + (col & 2047)] = f2bf(v);
        }
      }
}

// ---------------- bf16 GEMM v3: BM=256 x BN=256, BK=64, 8 waves (wave tile 128x64) ----------------
// EPI 3: qkv split (N=6144). EPI 5: interleaved gate/up (N=11264, B row 2c=gate_c,
// 2c+1=up_c): adjacent lanes hold (gate,up) for same c -> shfl_xor(1), even lanes
// store silu(g)*u to outB[row][col>>1] (stride INTERN).
template<int EPI>
__global__ __launch_bounds__(512, 2) void gemm3(const unsigned short* __restrict__ Ag,
                                                const unsigned short* __restrict__ Btg,
                                                int M, int N, int K, int nbx,
                                                float* __restrict__ outF,
                                                unsigned short* __restrict__ outB,
                                                const float* __restrict__ res,
                                                const unsigned short* __restrict__ gate,
                                                unsigned short* __restrict__ qb_,
                                                unsigned short* __restrict__ kb_,
                                                unsigned short* __restrict__ vb_) {
  __shared__ unsigned short As[2][256 * 64];
  __shared__ unsigned short Bs[2][256 * 64];
  const int tid = threadIdx.x;
  const int wid = tid >> 6, l = tid & 63;
  const int wr = wid >> 2, wc = wid & 3;        // 2 x 4 waves; wave tile 128 x 64
  const int lr = l & 15;
  const int lkb = ((l >> 4) & 3) << 4;
  const int arsw = (lr & 7) << 4;
  const int nwg = gridDim.x;
  const int orig = blockIdx.x;
  const int swz = (orig & 7) * (nwg >> 3) + (orig >> 3);
  const int m0 = (swz / nbx) * 256, n0 = (swz % nbx) * 256;
  const int arow = tid >> 3;
  const int scol = (((tid & 7) << 4) ^ ((arow & 7) << 4)) >> 1;

#define G3STAGE(T, B)                                                       \
  {                                                                         \
    const int k0_ = (T) << 6;                                               \
    _Pragma("unroll")                                                       \
    for (int i = 0; i < 4; ++i)                                             \
      gl_lds16(Ag + (size_t)(m0 + i * 64 + arow) * K + k0_ + scol,          \
               &As[B][(i * 512 + tid) * 8]);                                \
    _Pragma("unroll")                                                       \
    for (int i = 0; i < 4; ++i)                                             \
      gl_lds16(Btg + (size_t)(n0 + i * 64 + arow) * K + k0_ + scol,         \
               &Bs[B][(i * 512 + tid) * 8]);                                \
  }
#define LDA3(B, mf, ks) (*(const bf16x8*)&As[B][(wr * 128 + (mf) * 16 + lr) * 64 + (((((ks) << 6) | lkb) ^ arsw) >> 1)])
#define LDB3(B, nf, ks) (*(const bf16x8*)&Bs[B][(wc * 64 + (nf) * 16 + lr) * 64 + (((((ks) << 6) | lkb) ^ arsw) >> 1)])

  f32x4 acc[8][4];
#pragma unroll
  for (int i = 0; i < 8; ++i)
#pragma unroll
    for (int j = 0; j < 4; ++j) acc[i][j] = (f32x4){0.f, 0.f, 0.f, 0.f};

  G3STAGE(0, 0);
  G3STAGE(1, 1);
  asm volatile("s_waitcnt vmcnt(8)" ::: "memory");
  __builtin_amdgcn_sched_barrier(0);
  __builtin_amdgcn_s_barrier();

  const int NT = K >> 6;
  for (int t = 0; t < NT; ++t) {
    const int cur = t & 1;
    {
      bf16x8 a0[8], b0[4];
#pragma unroll
      for (int mf = 0; mf < 8; ++mf) a0[mf] = LDA3(cur, mf, 0);
#pragma unroll
      for (int nf = 0; nf < 4; ++nf) b0[nf] = LDB3(cur, nf, 0);
      __builtin_amdgcn_s_setprio(1);
#pragma unroll
      for (int mf = 0; mf < 8; ++mf)
#pragma unroll
        for (int nf = 0; nf < 4; ++nf)
          acc[mf][nf] = __builtin_amdgcn_mfma_f32_16x16x32_bf16(a0[mf], b0[nf], acc[mf][nf], 0, 0, 0);
      __builtin_amdgcn_s_setprio(0);
    }
    bf16x8 a1[8], b1[4];
#pragma unroll
    for (int mf = 0; mf < 8; ++mf) a1[mf] = LDA3(cur, mf, 1);
#pragma unroll
    for (int nf = 0; nf < 4; ++nf) b1[nf] = LDB3(cur, nf, 1);
    asm volatile("s_waitcnt lgkmcnt(0)" ::: "memory");
    __builtin_amdgcn_sched_barrier(0);
    __builtin_amdgcn_s_barrier();
    if (t + 2 < NT) G3STAGE(t + 2, cur);
    __builtin_amdgcn_s_setprio(1);
#pragma unroll
    for (int mf = 0; mf < 8; ++mf)
#pragma unroll
      for (int nf = 0; nf < 4; ++nf)
        acc[mf][nf] = __builtin_amdgcn_mfma_f32_16x16x32_bf16(a1[mf], b1[nf], acc[mf][nf], 0, 0, 0);
    __builtin_amdgcn_s_setprio(0);
    if (t + 2 < NT) { asm volatile("s_waitcnt vmcnt(8)" ::: "memory"); }
    else            { asm volatile("s_waitcnt vmcnt(0)" ::: "memory"); }
    __builtin_amdgcn_sched_barrier(0);
    __builtin_amdgcn_s_barrier();
  }
#undef G3STAGE
#undef LDA3
#undef LDB3

#pragma unroll
  for (int mf = 0; mf < 8; ++mf)
#pragma unroll
    for (int nf = 0; nf < 4; ++nf)
#pragma unroll
      for (int r = 0; r < 4; ++r) {
        const int row = m0 + wr * 128 + mf * 16 + (l >> 4) * 4 + r;
        const int col = n0 + wc * 64 + nf * 16 + lr;
        float v = acc[mf][nf][r];
        if (EPI == 0) {
          outB[(size_t)row * N + col] = f2bf(v);
        } else if (EPI == 1) {
          const size_t idx = (size_t)row * N + col;
          outF[idx] = res[idx] + v;
        } else if (EPI == 3) {
          unsigned short* dst = (col < 2048) ? qb_ : (col < 4096) ? kb_ : vb_;
          dst[(size_t)row * 2048 + (col & 2047)] = f2bf(v);
        } else if (EPI == 5) {
          // interleaved gate/up: even col = gate_c, odd col = up_c (c = col>>1)
          const float other = __shfl_xor(v, 1, 64);
          if ((lr & 1) == 0) {
            const float g = v, u = other;
            outB[(size_t)row * INTERN + (col >> 1)] = f2bf(u * g / (1.f + __expf(-g)));
          }
        }
      }
}

// ---------------- causal flash attention v5: both pair-jobs concurrent ----------------
__global__ __launch_bounds__(512) void attn_kernel(const unsigned short* __restrict__ Q,
                                                   const unsigned short* __restrict__ Kb,
                                                   const unsigned short* __restrict__ Vt,
                                                   unsigned short* __restrict__ Ob) {
  __shared__ unsigned short Ks[2][64 * 128];   // [kv][d], 256B rows, (row&15)<<4 swizzle
  __shared__ unsigned short Vs[2][128 * 64];   // [d][kv], 128B rows, (row&7)<<4 swizzle
  __shared__ float alS[8][32];
  __shared__ unsigned short pad[8192];         // occupancy limiter: LDS > 80KB -> 1 block/CU
  const int tid = threadIdx.x, w = tid >> 6, l = tid & 63;
  const int lq = l & 31, hi = l >> 5;
  const int bid = blockIdx.x;
  const int h = 2 * (bid & 7) + ((bid >> 3) & 1);   // head pinned to XCD (L2 affinity)
  const int pp = bid >> 4;                          // 0..15
  if (gridDim.y == 2) { pad[tid] = 1; Ob[0] = pad[tid ^ 1]; }  // never true; keeps pad live

  const int j = (w < 4) ? (31 - pp) : pp;   // job A (heavy) / job B (light)
  const int qb0 = j * 128;
  const int qw0 = qb0 + (w & 3) * 32;
  const int ntA = (31 - pp) * 2 + 2;        // block-uniform loop bound (job A range)

  bf16x8 qf[8];
#pragma unroll
  for (int cq = 0; cq < 8; ++cq)
    qf[cq] = *(const bf16x8*)(Q + (size_t)(qw0 + lq) * HIDN + h * HDIM + cq * 16 + hi * 8);

  float m2 = -1e30f, lsum = 0.f;
  f32x16 o[4];
#pragma unroll
  for (int dc = 0; dc < 4; ++dc) o[dc] = (f32x16){};

  const int krow = tid >> 4, kc2 = (tid & 15) * 16;
  const int vrow = tid >> 3, vc2 = (tid & 7) * 16;

#define STAGE(T, B)                                                                          \
  {                                                                                          \
    const int kv0_ = (T) * 64;                                                               \
    _Pragma("unroll")                                                                        \
    for (int i_ = 0; i_ < 2; ++i_) {                                                         \
      const int row = i_ * 32 + krow;                                                        \
      gl_lds16(Kb + (size_t)(kv0_ + row) * HIDN + h * HDIM + ((kc2 ^ ((row & 15) << 4)) >> 1), \
               &Ks[B][i_ * 4096 + tid * 8]);                                                 \
    }                                                                                        \
    _Pragma("unroll")                                                                        \
    for (int i_ = 0; i_ < 2; ++i_) {                                                         \
      const int row = i_ * 64 + vrow;                                                        \
      gl_lds16(Vt + (size_t)(h * HDIM + row) * SEQ + kv0_ + ((vc2 ^ ((row & 7) << 4)) >> 1),   \
               &Vs[B][i_ * 4096 + tid * 8]);                                                 \
    }                                                                                        \
  }
#define LDK(row_, c_) (*(const bf16x8*)&Ks[cur][(row_) * 128 + ((((c_) * 32 + hi * 16) ^ (((row_) & 15) << 4)) >> 1)])
#define LDV(row_, ks_) (*(const bf16x8*)&Vs[cur][(row_) * 64 + ((((ks_) * 32 + hi * 16) ^ (((row_) & 7) << 4)) >> 1)])

  STAGE(0, 0);
  __syncthreads();

  for (int t = 0; t < ntA; ++t) {
    const int cur = t & 1, kv0 = t * 64;
    if (t + 1 < ntA) STAGE(t + 1, cur ^ 1);

    if (kv0 <= qw0 + 31) {
      f32x16 s0 = {}, s1 = {};
      __builtin_amdgcn_s_setprio(1);
#pragma unroll
      for (int cq = 0; cq < 8; ++cq) {
        s0 = __builtin_amdgcn_mfma_f32_32x32x16_bf16(LDK(lq, cq), qf[cq], s0, 0, 0, 0);
        s1 = __builtin_amdgcn_mfma_f32_32x32x16_bf16(LDK(32 + lq, cq), qf[cq], s1, 0, 0, 0);
      }
      __builtin_amdgcn_s_setprio(0);
      const float SC2 = 0.08838834764831845f * 1.44269504088896f;
#pragma unroll
      for (int r = 0; r < 16; ++r) { s0[r] *= SC2; s1[r] *= SC2; }
      if (kv0 + 63 > qw0) {
        const int qi = qw0 + lq;
#pragma unroll
        for (int r = 0; r < 16; ++r) {
          const int kvr = kv0 + (r & 3) + 8 * (r >> 2) + 4 * hi;
          if (kvr > qi) s0[r] = -1e30f;
          if (kvr + 32 > qi) s1[r] = -1e30f;
        }
      }
      float vm = s0[0];
#pragma unroll
      for (int r = 1; r < 16; ++r) vm = fmaxf(vm, s0[r]);
#pragma unroll
      for (int r = 0; r < 16; ++r) vm = fmaxf(vm, s1[r]);
      vm = fmaxf(vm, __shfl_xor(vm, 32, 64));
      float al = 1.f;
      if (!__all(vm <= m2 + 11.54f)) {
        const float mn = fmaxf(m2, vm);
        al = exp2f(m2 - mn);
        m2 = mn;
        if (l < 32) alS[w][l] = al;
#pragma unroll
        for (int r = 0; r < 16; ++r) {
          const float a = alS[w][(r & 3) + 8 * (r >> 2) + 4 * hi];
          o[0][r] *= a; o[1][r] *= a; o[2][r] *= a; o[3][r] *= a;
        }
      }
      float p[32];
#pragma unroll
      for (int r = 0; r < 16; ++r) { p[r] = exp2f(s0[r] - m2); p[16 + r] = exp2f(s1[r] - m2); }
      float rsum = 0.f;
#pragma unroll
      for (int r = 0; r < 32; ++r) rsum += p[r];
      lsum = lsum * al + (rsum + __shfl_xor(rsum, 32, 64));
      bf16x8 pa[4];
#pragma unroll
      for (int hh = 0; hh < 2; ++hh) {
        unsigned ua[8];
#pragma unroll
        for (int i_ = 0; i_ < 8; ++i_) ua[i_] = cvtpk(p[hh * 16 + 2 * i_], p[hh * 16 + 2 * i_ + 1]);
        plswap(ua[0], ua[2]); plswap(ua[1], ua[3]);
        plswap(ua[4], ua[6]); plswap(ua[5], ua[7]);
        pa[hh * 2]     = mk_pa(ua[0], ua[1], ua[2], ua[3]);
        pa[hh * 2 + 1] = mk_pa(ua[4], ua[5], ua[6], ua[7]);
      }
      __builtin_amdgcn_s_setprio(1);
#pragma unroll
      for (int dc = 0; dc < 4; ++dc) {
        const int vr = dc * 32 + lq;
#pragma unroll
        for (int ks = 0; ks < 4; ++ks)
          o[dc] = __builtin_amdgcn_mfma_f32_32x32x16_bf16(pa[ks], LDV(vr, ks), o[dc], 0, 0, 0);
      }
      __builtin_amdgcn_s_setprio(0);
    }
    __syncthreads();
  }
#undef STAGE
#undef LDK
#undef LDV

  if (l < 32) alS[w][l] = 1.f / lsum;
#pragma unroll
  for (int r = 0; r < 16; ++r) {
    const int q = (r & 3) + 8 * (r >> 2) + 4 * hi;
    const float rr = alS[w][q];
    const size_t rowb = (size_t)(qw0 + q) * HIDN + h * HDIM + lq;
    Ob[rowb]      = f2bf(o[0][r] * rr);
    Ob[rowb + 32] = f2bf(o[1][r] * rr);
    Ob[rowb + 64] = f2bf(o[2][r] * rr);
    Ob[rowb + 96] = f2bf(o[3][r] * rr);
  }
}

extern "C" void kernel_launch(void* const* d_in, const int* in_sizes, int n_in,
                              void* d_out, int out_size, void* d_ws, size_t ws_size,
                              hipStream_t stream) {
  const float* x    = (const float*)d_in[0];
  const float* fcos = (const float*)d_in[1];
  const float* fsin = (const float*)d_in[2];
  // d_in[3] = mask: causal computed directly
  const float* wq = (const float*)d_in[4];
  const float* wk = (const float*)d_in[5];
  const float* wv = (const float*)d_in[6];
  const float* wo = (const float*)d_in[7];
  const float* wg = (const float*)d_in[8];
  const float* wu = (const float*)d_in[9];
  const float* wd = (const float*)d_in[10];
  const float* n1 = (const float*)d_in[11];
  const float* n2 = (const float*)d_in[12];
  float* out = (float*)d_out;

  const size_t HH = (size_t)HIDN * HIDN, HI = (size_t)HIDN * INTERN;
  const size_t SH = (size_t)SEQ * HIDN, SI = (size_t)SEQ * INTERN;
  unsigned short* p = (unsigned short*)d_ws;
  unsigned short* wqT = p; p += HH;   // wqT|wkT|wvT contiguous => fused QKV B [6144][2048]
  unsigned short* wkT = p; p += HH;
  unsigned short* wvT = p; p += HH;
  unsigned short* woT = p; p += HH;
  unsigned short* wguT = p; p += 2 * HI;  // interleaved gate/up B [11264][2048]
  unsigned short* wdT = p; p += HI;
  unsigned short* xn  = p; p += SH;   // xn, later hn
  unsigned short* qb  = p; p += SH;
  unsigned short* kb  = p; p += SH;
  unsigned short* vb  = p; p += SH;   // v, later attention out
  unsigned short* vt  = p; p += SH;
  unsigned short* ffnb = p; p += SI;
  float* hbuf = (float*)p;            // SH floats

  rmsnorm_kernel<<<SEQ, 256, 0, stream>>>(x, n1, xn);
  dim3 tHH(HIDN / 32, HIDN / 32);
  transpose_f2b<<<tHH, 256, 0, stream>>>(wq, wqT, HIDN, HIDN, 1, 0);
  transpose_f2b<<<tHH, 256, 0, stream>>>(wk, wkT, HIDN, HIDN, 1, 0);
  transpose_f2b<<<tHH, 256, 0, stream>>>(wv, wvT, HIDN, HIDN, 1, 0);
  transpose_f2b<<<tHH, 256, 0, stream>>>(wo, woT, HIDN, HIDN, 1, 0);
  transpose_f2b<<<dim3(INTERN / 32, HIDN / 32), 256, 0, stream>>>(wg, wguT, HIDN, INTERN, 2, 0);
  transpose_f2b<<<dim3(INTERN / 32, HIDN / 32), 256, 0, stream>>>(wu, wguT, HIDN, INTERN, 2, 1);
  transpose_f2b<<<dim3(HIDN / 32, INTERN / 32), 256, 0, stream>>>(wd, wdT, INTERN, HIDN, 1, 0);

  // fused QKV: C[4096][6144] on 256x256 tiles, split-stored into qb/kb/vb
  gemm3<3><<<384, 512, 0, stream>>>(xn, wqT, SEQ, 3 * HIDN, HIDN, 24,
                                    nullptr, nullptr, nullptr, nullptr, qb, kb, vb);
  rope_kernel<<<SEQ, 256, 0, stream>>>(qb, fcos, fsin);
  rope_kernel<<<SEQ, 256, 0, stream>>>(kb, fcos, fsin);
  transpose_b2b<<<dim3(HIDN / 32, SEQ / 32), 256, 0, stream>>>(vb, vt, SEQ, HIDN);
  attn_kernel<<<dim3(256), 512, 0, stream>>>(qb, kb, vt, vb);
  gemm2<1><<<256, 512, 0, stream>>>(vb, woT, SEQ, HIDN, HIDN, 8,
                                    hbuf, nullptr, x, nullptr, nullptr, nullptr, nullptr);
  rmsnorm_kernel<<<SEQ, 256, 0, stream>>>(hbuf, n2, xn);
  // fused+interleaved gate/up: C[4096][11264] -> silu(gate)*up stored directly to ffnb
  gemm3<5><<<704, 512, 0, stream>>>(xn, wguT, SEQ, 2 * INTERN, HIDN, 44,
                                    nullptr, ffnb, nullptr, nullptr, nullptr, nullptr, nullptr);
  gemm2<1><<<256, 512, 0, stream>>>(ffnb, wdT, SEQ, HIDN, INTERN, 8,
                                    out, nullptr, hbuf, nullptr, nullptr, nullptr, nullptr);
}